// Round 14
// baseline (72.993 us; speedup 1.0000x reference)
//
#include <hip/hip_runtime.h>
#include <hip/hip_bf16.h>

// GAT layer, N=4096, C_IN=C_OUT=256, HEADS=4, C_HEAD=64.
// Pipeline (2 kernels):
//  K1f: h = X@W^T + b in-register; writes hB (bf16 MFMA-B-fragment order)
//       + e_src/e_dst (x log2e). h fp32 never materialized.
//  K3f: masked softmax (fixed m=0) + P@H, ALL 4 HEADS per block, reading raw
//       adj exactly once (nontemporal, depth-2 register prefetch) — the
//       ~2.1 TB/s read-wall cost of adj overlaps the per-head VALU/MFMA work
//       instead of paying a separate ~30us pack kernel.
//       Block = 16 rows x 4096 j x 4 heads; 8 waves = 8 j-splits of 512 j;
//       grid 256 = 1 block/CU; 4 sequential per-head LDS merge passes.
// Workspace: ~2.2 MB.

#define NN 4096
#define LOG2E 1.4426950408889634f

typedef float f32x4 __attribute__((ext_vector_type(4)));
typedef int i32x4 __attribute__((ext_vector_type(4)));
typedef unsigned int u32x2 __attribute__((ext_vector_type(2)));
typedef unsigned int u32x4 __attribute__((ext_vector_type(4)));
typedef unsigned short u16x4 __attribute__((ext_vector_type(4)));
typedef unsigned short u16x8 __attribute__((ext_vector_type(8)));
typedef __bf16 bf16x8 __attribute__((ext_vector_type(8)));

__device__ __forceinline__ unsigned short f2bf_rne(float f) {
    unsigned int u = __builtin_bit_cast(unsigned int, f);
    u += 0x7fffu + ((u >> 16) & 1u);
    return (unsigned short)(u >> 16);
}

__device__ __forceinline__ bf16x8 ld_cvt8(const float* __restrict__ p) {
    f32x4 x = *(const f32x4*)p;
    f32x4 y = *(const f32x4*)(p + 4);
    u16x8 u;
    u[0] = f2bf_rne(x[0]); u[1] = f2bf_rne(x[1]); u[2] = f2bf_rne(x[2]); u[3] = f2bf_rne(x[3]);
    u[4] = f2bf_rne(y[0]); u[5] = f2bf_rne(y[1]); u[6] = f2bf_rne(y[2]); u[7] = f2bf_rne(y[3]);
    return __builtin_bit_cast(bf16x8, u);
}

// ---------------- K1f: fused GEMM + hB-swizzle + e_src/e_dst ----------------
// 256 blocks x 256 thr. Block = 16 rows; wave hh owns cols [64hh,64hh+64) = head hh.
__global__ __launch_bounds__(256) void k1_fused(const float* __restrict__ X,
                                                const float* __restrict__ W,
                                                const float* __restrict__ bias,
                                                const float* __restrict__ a,
                                                unsigned short* __restrict__ hB,
                                                float* __restrict__ esrc,
                                                float* __restrict__ edst) {
    const int lane = threadIdx.x & 63;
    const int hh   = threadIdx.x >> 6;      // head / column group
    const int row  = lane & 15;
    const int kg   = lane >> 4;
    const int rowbase = blockIdx.x * 16;

    f32x4 acc[4];
#pragma unroll
    for (int n = 0; n < 4; ++n) acc[n] = (f32x4)0.f;

#pragma unroll
    for (int kk = 0; kk < 8; ++kk) {
        const int kb = kk * 32 + kg * 8;
        bf16x8 a0 = ld_cvt8(X + (rowbase + row) * 256 + kb);
#pragma unroll
        for (int n = 0; n < 4; ++n) {
            bf16x8 bb = ld_cvt8(W + (hh * 64 + n * 16 + row) * 256 + kb);
            acc[n] = __builtin_amdgcn_mfma_f32_16x16x32_bf16(a0, bb, acc[n], 0, 0, 0);
        }
    }

    // epilogue: bias, hB store (fragment order), e_src/e_dst dots
    const int t   = rowbase >> 5;
    const int lp  = (((rowbase >> 4) & 1) * 2 + (kg >> 1)) * 16 + row;
    const int eoff = (kg & 1) * 4;
    unsigned short* hbb = hB + (hh * 128 + t) * 2048 + lp * 8 + eoff;

    float eS0 = 0.f, eS1 = 0.f, eS2 = 0.f, eS3 = 0.f;
    float eT0 = 0.f, eT1 = 0.f, eT2 = 0.f, eT3 = 0.f;
#pragma unroll
    for (int n = 0; n < 4; ++n) {
        const int col = hh * 64 + n * 16 + row;
        const float bv = bias[col];
        f32x4 hv;
        hv[0] = acc[n][0] + bv; hv[1] = acc[n][1] + bv;
        hv[2] = acc[n][2] + bv; hv[3] = acc[n][3] + bv;
        u16x4 us;
        us[0] = f2bf_rne(hv[0]); us[1] = f2bf_rne(hv[1]);
        us[2] = f2bf_rne(hv[2]); us[3] = f2bf_rne(hv[3]);
        *(u16x4*)(hbb + n * 512) = us;
        const float as_ = a[hh * 128 + n * 16 + row];
        const float ad_ = a[hh * 128 + 64 + n * 16 + row];
        eS0 += hv[0] * as_; eS1 += hv[1] * as_; eS2 += hv[2] * as_; eS3 += hv[3] * as_;
        eT0 += hv[0] * ad_; eT1 += hv[1] * ad_; eT2 += hv[2] * ad_; eT3 += hv[3] * ad_;
    }
#pragma unroll
    for (int d = 1; d < 16; d <<= 1) {
        eS0 += __shfl_xor(eS0, d); eS1 += __shfl_xor(eS1, d);
        eS2 += __shfl_xor(eS2, d); eS3 += __shfl_xor(eS3, d);
        eT0 += __shfl_xor(eT0, d); eT1 += __shfl_xor(eT1, d);
        eT2 += __shfl_xor(eT2, d); eT3 += __shfl_xor(eT3, d);
    }
    if (row == 0) {
        const int rb = hh * NN + rowbase + kg * 4;
        esrc[rb + 0] = eS0 * LOG2E; esrc[rb + 1] = eS1 * LOG2E;
        esrc[rb + 2] = eS2 * LOG2E; esrc[rb + 3] = eS3 * LOG2E;
        edst[rb + 0] = eT0 * LOG2E; edst[rb + 1] = eT1 * LOG2E;
        edst[rb + 2] = eT2 * LOG2E; edst[rb + 3] = eT3 * LOG2E;
    }
}

// ---------------- K3f: 4-head fused masked softmax (m=0) + P@H ----------------
// grid 256: ib = bx, rows i0 = ib*16 .. +16, all 4096 j, all 4 heads.
// 8 waves = 8 j-splits of 512 j = 16 tiles of 32 j.
// Lane (row,kg) covers j = q*512 + tl*32 + kg*8 + [0,8).
__global__ __launch_bounds__(512, 2) void k3_fused(const int* __restrict__ adj,
                                                   const unsigned short* __restrict__ hB,
                                                   const float* __restrict__ esrc,
                                                   const float* __restrict__ edst,
                                                   float* __restrict__ out) {
    __shared__ float lacc[8][16][64];
    __shared__ float lls[8][16];
    __shared__ u32x2 mlut[16];

    const int lane = threadIdx.x & 63;
    const int q  = threadIdx.x >> 6;  // j-split 0..7 (512 j each)
    const int i0 = blockIdx.x * 16;
    const int row = lane & 15;
    const int kg  = lane >> 4;
    const int kg8 = kg * 8;

    if (threadIdx.x < 16) {
        const unsigned n = threadIdx.x;
        u32x2 m;
        m[0] = ((n & 1u) ? 0xFFFFu : 0u) | ((n & 2u) ? 0xFFFF0000u : 0u);
        m[1] = ((n & 4u) ? 0xFFFFu : 0u) | ((n & 8u) ? 0xFFFF0000u : 0u);
        mlut[n] = m;
    }
    __syncthreads();

    float es[4];
#pragma unroll
    for (int h = 0; h < 4; ++h) es[h] = esrc[h * NN + i0 + row];

    const unsigned int* adjp = (const unsigned int*)adj
        + (size_t)(i0 + row) * NN + q * 512 + kg8;
    const float* eD[4];
    const unsigned short* hBp[4];
#pragma unroll
    for (int h = 0; h < 4; ++h) {
        eD[h]  = edst + h * NN + q * 512 + kg8;
        hBp[h] = hB + (size_t)((h * 128 + q * 16) * 256 + lane) * 8;
    }

    // ones B-fragment: column 0 only
    u16x8 ou;
    const unsigned short ov = (row == 0) ? (unsigned short)0x3F80 : (unsigned short)0;
#pragma unroll
    for (int e = 0; e < 8; ++e) ou[e] = ov;
    const bf16x8 bOnes = __builtin_bit_cast(bf16x8, ou);

    f32x4 acc[4][5];
#pragma unroll
    for (int h = 0; h < 4; ++h)
#pragma unroll
        for (int n = 0; n < 5; ++n) acc[h][n] = (f32x4)0.f;

    // depth-2 nontemporal prefetch of the adj stream
    u32x4 c0 = __builtin_nontemporal_load((const u32x4*)(adjp));
    u32x4 c1 = __builtin_nontemporal_load((const u32x4*)(adjp + 4));

    for (int tl = 0; tl < 16; ++tl) {
        u32x4 n0, n1;
        if (tl < 15) {
            n0 = __builtin_nontemporal_load((const u32x4*)(adjp + (tl + 1) * 32));
            n1 = __builtin_nontemporal_load((const u32x4*)(adjp + (tl + 1) * 32 + 4));
        }
        const unsigned m8 = (c0[0] & 1u)        | ((c0[1] & 1u) << 1)
                          | ((c0[2] & 1u) << 2) | ((c0[3] & 1u) << 3)
                          | ((c1[0] & 1u) << 4) | ((c1[1] & 1u) << 5)
                          | ((c1[2] & 1u) << 6) | ((c1[3] & 1u) << 7);
        const u32x2 mk0 = mlut[m8 & 15u];
        const u32x2 mk1 = mlut[(m8 >> 4) & 15u];

#pragma unroll
        for (int h = 0; h < 4; ++h) {
            const f32x4 E0 = *(const f32x4*)(eD[h] + tl * 32);
            const f32x4 E1 = *(const f32x4*)(eD[h] + tl * 32 + 4);
            const u16x8 B0 = *(const u16x8*)(hBp[h] + tl * 2048);
            const u16x8 B1 = *(const u16x8*)(hBp[h] + tl * 2048 + 512);
            const u16x8 B2 = *(const u16x8*)(hBp[h] + tl * 2048 + 1024);
            const u16x8 B3 = *(const u16x8*)(hBp[h] + tl * 2048 + 1536);
            f32x4 s0v = E0 + (f32x4)(es[h]);
            f32x4 s1v = E1 + (f32x4)(es[h]);
            s0v = __builtin_elementwise_max(s0v, s0v * 0.2f);
            s1v = __builtin_elementwise_max(s1v, s1v * 0.2f);
            bf16x8 af;
            af[0] = (__bf16)__builtin_exp2f(s0v[0]);
            af[1] = (__bf16)__builtin_exp2f(s0v[1]);
            af[2] = (__bf16)__builtin_exp2f(s0v[2]);
            af[3] = (__bf16)__builtin_exp2f(s0v[3]);
            af[4] = (__bf16)__builtin_exp2f(s1v[0]);
            af[5] = (__bf16)__builtin_exp2f(s1v[1]);
            af[6] = (__bf16)__builtin_exp2f(s1v[2]);
            af[7] = (__bf16)__builtin_exp2f(s1v[3]);
            u32x4 aw = __builtin_bit_cast(u32x4, af);
            aw[0] &= mk0[0]; aw[1] &= mk0[1];
            aw[2] &= mk1[0]; aw[3] &= mk1[1];
            af = __builtin_bit_cast(bf16x8, aw);
            acc[h][0] = __builtin_amdgcn_mfma_f32_16x16x32_bf16(af, __builtin_bit_cast(bf16x8, B0), acc[h][0], 0, 0, 0);
            acc[h][1] = __builtin_amdgcn_mfma_f32_16x16x32_bf16(af, __builtin_bit_cast(bf16x8, B1), acc[h][1], 0, 0, 0);
            acc[h][2] = __builtin_amdgcn_mfma_f32_16x16x32_bf16(af, __builtin_bit_cast(bf16x8, B2), acc[h][2], 0, 0, 0);
            acc[h][3] = __builtin_amdgcn_mfma_f32_16x16x32_bf16(af, __builtin_bit_cast(bf16x8, B3), acc[h][3], 0, 0, 0);
            acc[h][4] = __builtin_amdgcn_mfma_f32_16x16x32_bf16(af, bOnes, acc[h][4], 0, 0, 0);
        }
        c0 = n0; c1 = n1;
    }

    // ---- 4 sequential per-head merge passes ----
#pragma unroll
    for (int h = 0; h < 4; ++h) {
#pragma unroll
        for (int n = 0; n < 4; ++n) {
#pragma unroll
            for (int r = 0; r < 4; ++r)
                lacc[q][kg * 4 + r][n * 16 + row] = acc[h][n][r];
        }
        if (row == 0) {
#pragma unroll
            for (int r = 0; r < 4; ++r) lls[q][kg * 4 + r] = acc[h][4][r];
        }
        __syncthreads();
        if (threadIdx.x < 256) {
            const int idx = threadIdx.x * 4;
            const int r2 = idx >> 6;
            const int c  = idx & 63;
            f32x4 v = (f32x4)0.f;
            float l = 0.f;
#pragma unroll
            for (int q2 = 0; q2 < 8; ++q2) {
                v += *(const f32x4*)&lacc[q2][r2][c];
                l += lls[q2][r2];
            }
            const float inv = 1.f / l;
            f32x4 o;
            o[0] = v[0] * inv; o[1] = v[1] * inv; o[2] = v[2] * inv; o[3] = v[3] * inv;
            *(f32x4*)(out + (i0 + r2) * 256 + h * 64 + c) = o;
        }
        __syncthreads();
    }
}

extern "C" void kernel_launch(void* const* d_in, const int* in_sizes, int n_in,
                              void* d_out, int out_size, void* d_ws, size_t ws_size,
                              hipStream_t stream) {
    const float* X    = (const float*)d_in[0];
    const int*   adj  = (const int*)d_in[1];
    const float* W    = (const float*)d_in[2];
    const float* bias = (const float*)d_in[3];
    const float* a    = (const float*)d_in[4];
    float* out = (float*)d_out;

    char* ws = (char*)d_ws;
    unsigned short* hB   = (unsigned short*)(ws);                         // 2 MB
    float*          esrc = (float*)(ws + (2 << 20));                      // 64 KB (HEADS*N)
    float*          edst = (float*)(ws + (2 << 20) + (64 << 10));         // 64 KB (HEADS*N)

    k1_fused<<<256, 256, 0, stream>>>(X, W, bias, a, hB, esrc, edst);
    k3_fused<<<256, 512, 0, stream>>>(adj, hB, esrc, edst, out);
}

// Round 15
// 72.971 us; speedup vs baseline: 1.0003x; 1.0003x over previous
//
#include <hip/hip_runtime.h>
#include <hip/hip_bf16.h>

// GAT layer, N=4096, C_IN=C_OUT=256, HEADS=4, C_HEAD=64.
// Pipeline (2 kernels):
//  K1f: h = X@W^T + b in-register; writes hB (bf16 MFMA-B-fragment order)
//       + e_src/e_dst (x log2e). h fp32 never materialized.
//  K3f: masked softmax (fixed m=0) + P@H, ALL 4 HEADS per block, reading raw
//       adj exactly once (nontemporal, depth-2 register prefetch) — the
//       ~2.1 TB/s read-wall cost of adj overlaps the per-head VALU/MFMA work
//       instead of paying a separate ~30us pack kernel.
//       Block = 16 rows x 4096 j x 4 heads; 8 waves = 8 j-splits of 512 j;
//       grid 256 = 1 block/CU; 4 sequential per-head LDS merge passes.
// Workspace: ~2.2 MB.

#define NN 4096
#define LOG2E 1.4426950408889634f

typedef float f32x4 __attribute__((ext_vector_type(4)));
typedef int i32x4 __attribute__((ext_vector_type(4)));
typedef unsigned int u32x2 __attribute__((ext_vector_type(2)));
typedef unsigned int u32x4 __attribute__((ext_vector_type(4)));
typedef unsigned short u16x4 __attribute__((ext_vector_type(4)));
typedef unsigned short u16x8 __attribute__((ext_vector_type(8)));
typedef __bf16 bf16x8 __attribute__((ext_vector_type(8)));

__device__ __forceinline__ unsigned short f2bf_rne(float f) {
    unsigned int u = __builtin_bit_cast(unsigned int, f);
    u += 0x7fffu + ((u >> 16) & 1u);
    return (unsigned short)(u >> 16);
}

__device__ __forceinline__ bf16x8 ld_cvt8(const float* __restrict__ p) {
    f32x4 x = *(const f32x4*)p;
    f32x4 y = *(const f32x4*)(p + 4);
    u16x8 u;
    u[0] = f2bf_rne(x[0]); u[1] = f2bf_rne(x[1]); u[2] = f2bf_rne(x[2]); u[3] = f2bf_rne(x[3]);
    u[4] = f2bf_rne(y[0]); u[5] = f2bf_rne(y[1]); u[6] = f2bf_rne(y[2]); u[7] = f2bf_rne(y[3]);
    return __builtin_bit_cast(bf16x8, u);
}

// ---------------- K1f: fused GEMM + hB-swizzle + e_src/e_dst ----------------
// 256 blocks x 256 thr. Block = 16 rows; wave hh owns cols [64hh,64hh+64) = head hh.
__global__ __launch_bounds__(256) void k1_fused(const float* __restrict__ X,
                                                const float* __restrict__ W,
                                                const float* __restrict__ bias,
                                                const float* __restrict__ a,
                                                unsigned short* __restrict__ hB,
                                                float* __restrict__ esrc,
                                                float* __restrict__ edst) {
    const int lane = threadIdx.x & 63;
    const int hh   = threadIdx.x >> 6;      // head / column group
    const int row  = lane & 15;
    const int kg   = lane >> 4;
    const int rowbase = blockIdx.x * 16;

    f32x4 acc[4];
#pragma unroll
    for (int n = 0; n < 4; ++n) acc[n] = (f32x4)0.f;

#pragma unroll
    for (int kk = 0; kk < 8; ++kk) {
        const int kb = kk * 32 + kg * 8;
        bf16x8 a0 = ld_cvt8(X + (rowbase + row) * 256 + kb);
#pragma unroll
        for (int n = 0; n < 4; ++n) {
            bf16x8 bb = ld_cvt8(W + (hh * 64 + n * 16 + row) * 256 + kb);
            acc[n] = __builtin_amdgcn_mfma_f32_16x16x32_bf16(a0, bb, acc[n], 0, 0, 0);
        }
    }

    // epilogue: bias, hB store (fragment order), e_src/e_dst dots
    const int t   = rowbase >> 5;
    const int lp  = (((rowbase >> 4) & 1) * 2 + (kg >> 1)) * 16 + row;
    const int eoff = (kg & 1) * 4;
    unsigned short* hbb = hB + (hh * 128 + t) * 2048 + lp * 8 + eoff;

    float eS0 = 0.f, eS1 = 0.f, eS2 = 0.f, eS3 = 0.f;
    float eT0 = 0.f, eT1 = 0.f, eT2 = 0.f, eT3 = 0.f;
#pragma unroll
    for (int n = 0; n < 4; ++n) {
        const int col = hh * 64 + n * 16 + row;
        const float bv = bias[col];
        f32x4 hv;
        hv[0] = acc[n][0] + bv; hv[1] = acc[n][1] + bv;
        hv[2] = acc[n][2] + bv; hv[3] = acc[n][3] + bv;
        u16x4 us;
        us[0] = f2bf_rne(hv[0]); us[1] = f2bf_rne(hv[1]);
        us[2] = f2bf_rne(hv[2]); us[3] = f2bf_rne(hv[3]);
        *(u16x4*)(hbb + n * 512) = us;
        const float as_ = a[hh * 128 + n * 16 + row];
        const float ad_ = a[hh * 128 + 64 + n * 16 + row];
        eS0 += hv[0] * as_; eS1 += hv[1] * as_; eS2 += hv[2] * as_; eS3 += hv[3] * as_;
        eT0 += hv[0] * ad_; eT1 += hv[1] * ad_; eT2 += hv[2] * ad_; eT3 += hv[3] * ad_;
    }
#pragma unroll
    for (int d = 1; d < 16; d <<= 1) {
        eS0 += __shfl_xor(eS0, d); eS1 += __shfl_xor(eS1, d);
        eS2 += __shfl_xor(eS2, d); eS3 += __shfl_xor(eS3, d);
        eT0 += __shfl_xor(eT0, d); eT1 += __shfl_xor(eT1, d);
        eT2 += __shfl_xor(eT2, d); eT3 += __shfl_xor(eT3, d);
    }
    if (row == 0) {
        const int rb = hh * NN + rowbase + kg * 4;
        esrc[rb + 0] = eS0 * LOG2E; esrc[rb + 1] = eS1 * LOG2E;
        esrc[rb + 2] = eS2 * LOG2E; esrc[rb + 3] = eS3 * LOG2E;
        edst[rb + 0] = eT0 * LOG2E; edst[rb + 1] = eT1 * LOG2E;
        edst[rb + 2] = eT2 * LOG2E; edst[rb + 3] = eT3 * LOG2E;
    }
}

// ---------------- K3f: 4-head fused masked softmax (m=0) + P@H ----------------
// grid 256: ib = bx, rows i0 = ib*16 .. +16, all 4096 j, all 4 heads.
// 8 waves = 8 j-splits of 512 j = 16 tiles of 32 j.
// Lane (row,kg) covers j = q*512 + tl*32 + kg*8 + [0,8).
__global__ __launch_bounds__(512, 2) void k3_fused(const int* __restrict__ adj,
                                                   const unsigned short* __restrict__ hB,
                                                   const float* __restrict__ esrc,
                                                   const float* __restrict__ edst,
                                                   float* __restrict__ out) {
    __shared__ float lacc[8][16][64];
    __shared__ float lls[8][16];
    __shared__ u32x2 mlut[16];

    const int lane = threadIdx.x & 63;
    const int q  = threadIdx.x >> 6;  // j-split 0..7 (512 j each)
    const int i0 = blockIdx.x * 16;
    const int row = lane & 15;
    const int kg  = lane >> 4;
    const int kg8 = kg * 8;

    if (threadIdx.x < 16) {
        const unsigned n = threadIdx.x;
        u32x2 m;
        m[0] = ((n & 1u) ? 0xFFFFu : 0u) | ((n & 2u) ? 0xFFFF0000u : 0u);
        m[1] = ((n & 4u) ? 0xFFFFu : 0u) | ((n & 8u) ? 0xFFFF0000u : 0u);
        mlut[n] = m;
    }
    __syncthreads();

    float es[4];
#pragma unroll
    for (int h = 0; h < 4; ++h) es[h] = esrc[h * NN + i0 + row];

    const unsigned int* adjp = (const unsigned int*)adj
        + (size_t)(i0 + row) * NN + q * 512 + kg8;
    const float* eD[4];
    const unsigned short* hBp[4];
#pragma unroll
    for (int h = 0; h < 4; ++h) {
        eD[h]  = edst + h * NN + q * 512 + kg8;
        hBp[h] = hB + (size_t)((h * 128 + q * 16) * 256 + lane) * 8;
    }

    // ones B-fragment: column 0 only
    u16x8 ou;
    const unsigned short ov = (row == 0) ? (unsigned short)0x3F80 : (unsigned short)0;
#pragma unroll
    for (int e = 0; e < 8; ++e) ou[e] = ov;
    const bf16x8 bOnes = __builtin_bit_cast(bf16x8, ou);

    f32x4 acc[4][5];
#pragma unroll
    for (int h = 0; h < 4; ++h)
#pragma unroll
        for (int n = 0; n < 5; ++n) acc[h][n] = (f32x4)0.f;

    // depth-2 nontemporal prefetch of the adj stream
    u32x4 c0 = __builtin_nontemporal_load((const u32x4*)(adjp));
    u32x4 c1 = __builtin_nontemporal_load((const u32x4*)(adjp + 4));

    for (int tl = 0; tl < 16; ++tl) {
        u32x4 n0, n1;
        if (tl < 15) {
            n0 = __builtin_nontemporal_load((const u32x4*)(adjp + (tl + 1) * 32));
            n1 = __builtin_nontemporal_load((const u32x4*)(adjp + (tl + 1) * 32 + 4));
        }
        const unsigned m8 = (c0[0] & 1u)        | ((c0[1] & 1u) << 1)
                          | ((c0[2] & 1u) << 2) | ((c0[3] & 1u) << 3)
                          | ((c1[0] & 1u) << 4) | ((c1[1] & 1u) << 5)
                          | ((c1[2] & 1u) << 6) | ((c1[3] & 1u) << 7);
        const u32x2 mk0 = mlut[m8 & 15u];
        const u32x2 mk1 = mlut[(m8 >> 4) & 15u];

#pragma unroll
        for (int h = 0; h < 4; ++h) {
            const f32x4 E0 = *(const f32x4*)(eD[h] + tl * 32);
            const f32x4 E1 = *(const f32x4*)(eD[h] + tl * 32 + 4);
            const u16x8 B0 = *(const u16x8*)(hBp[h] + tl * 2048);
            const u16x8 B1 = *(const u16x8*)(hBp[h] + tl * 2048 + 512);
            const u16x8 B2 = *(const u16x8*)(hBp[h] + tl * 2048 + 1024);
            const u16x8 B3 = *(const u16x8*)(hBp[h] + tl * 2048 + 1536);
            f32x4 s0v = E0 + (f32x4)(es[h]);
            f32x4 s1v = E1 + (f32x4)(es[h]);
            s0v = __builtin_elementwise_max(s0v, s0v * 0.2f);
            s1v = __builtin_elementwise_max(s1v, s1v * 0.2f);
            bf16x8 af;
            af[0] = (__bf16)__builtin_exp2f(s0v[0]);
            af[1] = (__bf16)__builtin_exp2f(s0v[1]);
            af[2] = (__bf16)__builtin_exp2f(s0v[2]);
            af[3] = (__bf16)__builtin_exp2f(s0v[3]);
            af[4] = (__bf16)__builtin_exp2f(s1v[0]);
            af[5] = (__bf16)__builtin_exp2f(s1v[1]);
            af[6] = (__bf16)__builtin_exp2f(s1v[2]);
            af[7] = (__bf16)__builtin_exp2f(s1v[3]);
            u32x4 aw = __builtin_bit_cast(u32x4, af);
            aw[0] &= mk0[0]; aw[1] &= mk0[1];
            aw[2] &= mk1[0]; aw[3] &= mk1[1];
            af = __builtin_bit_cast(bf16x8, aw);
            acc[h][0] = __builtin_amdgcn_mfma_f32_16x16x32_bf16(af, __builtin_bit_cast(bf16x8, B0), acc[h][0], 0, 0, 0);
            acc[h][1] = __builtin_amdgcn_mfma_f32_16x16x32_bf16(af, __builtin_bit_cast(bf16x8, B1), acc[h][1], 0, 0, 0);
            acc[h][2] = __builtin_amdgcn_mfma_f32_16x16x32_bf16(af, __builtin_bit_cast(bf16x8, B2), acc[h][2], 0, 0, 0);
            acc[h][3] = __builtin_amdgcn_mfma_f32_16x16x32_bf16(af, __builtin_bit_cast(bf16x8, B3), acc[h][3], 0, 0, 0);
            acc[h][4] = __builtin_amdgcn_mfma_f32_16x16x32_bf16(af, bOnes, acc[h][4], 0, 0, 0);
        }
        c0 = n0; c1 = n1;
    }

    // ---- 4 sequential per-head merge passes ----
#pragma unroll
    for (int h = 0; h < 4; ++h) {
#pragma unroll
        for (int n = 0; n < 4; ++n) {
#pragma unroll
            for (int r = 0; r < 4; ++r)
                lacc[q][kg * 4 + r][n * 16 + row] = acc[h][n][r];
        }
        if (row == 0) {
#pragma unroll
            for (int r = 0; r < 4; ++r) lls[q][kg * 4 + r] = acc[h][4][r];
        }
        __syncthreads();
        if (threadIdx.x < 256) {
            const int idx = threadIdx.x * 4;
            const int r2 = idx >> 6;
            const int c  = idx & 63;
            f32x4 v = (f32x4)0.f;
            float l = 0.f;
#pragma unroll
            for (int q2 = 0; q2 < 8; ++q2) {
                v += *(const f32x4*)&lacc[q2][r2][c];
                l += lls[q2][r2];
            }
            const float inv = 1.f / l;
            f32x4 o;
            o[0] = v[0] * inv; o[1] = v[1] * inv; o[2] = v[2] * inv; o[3] = v[3] * inv;
            *(f32x4*)(out + (i0 + r2) * 256 + h * 64 + c) = o;
        }
        __syncthreads();
    }
}

extern "C" void kernel_launch(void* const* d_in, const int* in_sizes, int n_in,
                              void* d_out, int out_size, void* d_ws, size_t ws_size,
                              hipStream_t stream) {
    const float* X    = (const float*)d_in[0];
    const int*   adj  = (const int*)d_in[1];
    const float* W    = (const float*)d_in[2];
    const float* bias = (const float*)d_in[3];
    const float* a    = (const float*)d_in[4];
    float* out = (float*)d_out;

    char* ws = (char*)d_ws;
    unsigned short* hB   = (unsigned short*)(ws);                         // 2 MB
    float*          esrc = (float*)(ws + (2 << 20));                      // 64 KB (HEADS*N)
    float*          edst = (float*)(ws + (2 << 20) + (64 << 10));         // 64 KB (HEADS*N)

    k1_fused<<<256, 256, 0, stream>>>(X, W, bias, a, hB, esrc, edst);
    k3_fused<<<256, 512, 0, stream>>>(adj, hB, esrc, edst, out);
}